// Round 3
// baseline (334.098 us; speedup 1.0000x reference)
//
#include <hip/hip_runtime.h>
#include <hip/hip_bf16.h>
#include <math.h>

#define BATCH 16
#define CIN   128
#define COUT  256
#define HH    56
#define WW    56
#define HW    3136
#define NTAP  9
#define NE    (COUT*CIN*NTAP)   // 294912

typedef short short8 __attribute__((ext_vector_type(8)));
typedef float floatx4 __attribute__((ext_vector_type(4)));

// workspace layout (byte offsets, all 256-aligned)
#define WSB_CTX   0                          // fp32 [16][128]
#define WSB_ASP   8192                       // fp32 [16][16] (9 used)
#define WSB_AIN   9472                       // fp32 [16][128]
#define WSB_AOUT  17664                      // fp32 [16][256]
#define WSB_ZP    34048                      // 4096 B of zeros (conv halo source)
#define WSB_XT    38144                      // bf16 [16][3136][128]
#define WSB_DYN   (WSB_XT + BATCH*HW*CIN*2)  // bf16 [16][9][256][128]  (tap,oc,ic)

// fp32 -> bf16 RNE
static __device__ inline unsigned short f2b(float f) {
    union { float f; unsigned u; } v; v.f = f;
    unsigned r = v.u + 0x7FFF + ((v.u >> 16) & 1);
    return (unsigned short)(r >> 16);
}
static __device__ inline short8 pack8(float4 a, float4 b) {
    short8 r;
    r[0] = (short)f2b(a.x); r[1] = (short)f2b(a.y); r[2] = (short)f2b(a.z); r[3] = (short)f2b(a.w);
    r[4] = (short)f2b(b.x); r[5] = (short)f2b(b.y); r[6] = (short)f2b(b.z); r[7] = (short)f2b(b.w);
    return r;
}

// async global->LDS, 16B per lane; LDS dst = wave-uniform base + lane*16
typedef const __attribute__((address_space(1))) void* gas_ptr;
typedef __attribute__((address_space(3))) void* las_ptr;
static __device__ __forceinline__ void gl_lds16(const void* g, void* l) {
    __builtin_amdgcn_global_load_lds((gas_ptr)g, (las_ptr)l, 16, 0, 0);
}

// ---------------------------------------------------------------------------
// K1: context[b,c] = mean(x[b,c,:,:]); block 0 also zeroes the conv zero-page
__global__ void k_context(const float* __restrict__ x, float* __restrict__ ctx,
                          float* __restrict__ zp) {
    int bc = blockIdx.x;
    if (bc == 0 && threadIdx.x < 64) {
        uint4 z = {0u, 0u, 0u, 0u};
        ((uint4*)zp)[threadIdx.x] = z;   // 1024 B of zeros
    }
    const float4* p = (const float4*)(x + (size_t)bc * HW);
    float s = 0.f;
    for (int i = threadIdx.x; i < HW / 4; i += 256) { float4 v = p[i]; s += v.x + v.y + v.z + v.w; }
    for (int off = 32; off; off >>= 1) s += __shfl_down(s, off, 64);
    __shared__ float red[4];
    if ((threadIdx.x & 63) == 0) red[threadIdx.x >> 6] = s;
    __syncthreads();
    if (threadIdx.x == 0) ctx[bc] = (red[0] + red[1] + red[2] + red[3]) * (1.f / (float)HW);
}

// ---------------------------------------------------------------------------
// K2: small gates — one wave per GEMV row
__global__ void k_attn(const float* __restrict__ ctx,
                       const float* __restrict__ wsp, const float* __restrict__ bsp,
                       const float* __restrict__ win, const float* __restrict__ bin,
                       const float* __restrict__ wout, const float* __restrict__ bout,
                       float* __restrict__ asp, float* __restrict__ ain, float* __restrict__ aout) {
    int R = blockIdx.x * 4 + (threadIdx.x >> 6);
    int lane = threadIdx.x & 63;
    int b = R / 393, r = R % 393;
    const float* w; float bias; float* o;
    if (r < 9)        { w = wsp  + r * CIN;         bias = bsp[r];         o = asp  + b * 16  + r; }
    else if (r < 137) { w = win  + (r - 9) * CIN;   bias = bin[r - 9];     o = ain  + b * CIN + (r - 9); }
    else              { w = wout + (r - 137) * CIN; bias = bout[r - 137];  o = aout + b * COUT + (r - 137); }
    float2 wv = ((const float2*)w)[lane];
    float2 cv = ((const float2*)(ctx + b * CIN))[lane];
    float d = wv.x * cv.x + wv.y * cv.y;
    for (int off = 32; off; off >>= 1) d += __shfl_down(d, off, 64);
    if (lane == 0) *o = 1.f / (1.f + __expf(-(d + bias)));
}

// ---------------------------------------------------------------------------
// K3 fat kernel: blocks [0,784) do the x transpose+cast (xt), blocks
// [784, 784+512) do the dyn build.
// BUILD v2: each block covers 576 CONTIGUOUS wk rows (e = (oc*128+ic)*9+tap,
// e0 = bid*576) -> one dense 0.29 MB sequential HBM stream per block instead
// of 512-B rows at 4608-B stride (DRAM-efficiency fix). (oc,ic,tap) decoded
// per-lane from e; results staged in LDS [tap][b][site] then written out as
// coalesced 128-B runs per (b,tap).
#define XT_BLOCKS    784          // 49 * 16
#define BUILD_BLOCKS 512          // NE / 576
__global__ void k_fat(const float* __restrict__ x, unsigned short* __restrict__ xt,
                      const float* __restrict__ ctx, const float* __restrict__ wk,
                      const float* __restrict__ bk, const float* __restrict__ base,
                      const float* __restrict__ asp, const float* __restrict__ ain,
                      const float* __restrict__ aout, unsigned short* __restrict__ dyn) {
    __shared__ unsigned short s_res[9 * 16 * 64];   // [tap][b][site-local] 18 KB
    if (blockIdx.x < XT_BLOCKS) {
        // ---- xt: [b][pix][ic] bf16; thread: 1 pixel x 32 ic ----
        int bid = blockIdx.x;
        int b = bid / 49;
        int p = (bid % 49) * 64 + (threadIdx.x & 63);
        int icq = threadIdx.x >> 6;
        const float* xb = x + (size_t)b * CIN * HW + p;
        unsigned short tmp[32];
#pragma unroll
        for (int j = 0; j < 32; ++j) tmp[j] = f2b(xb[(size_t)(icq * 32 + j) * HW]);
        uint4* dst = (uint4*)(xt + ((size_t)b * HW + p) * CIN + icq * 32);
        const uint4* s = (const uint4*)tmp;
        dst[0] = s[0]; dst[1] = s[1]; dst[2] = s[2]; dst[3] = s[3];
        return;
    }
    // ---- build v2: dense-stream skinny MFMA GEMM ----
    int bid = blockIdx.x - XT_BLOCKS;      // 0..511
    int wid = threadIdx.x >> 6, l = threadIdx.x & 63;
    int lq = l & 15, quad = l >> 4;
    int e0    = bid * 576;                 // first wk row of this block
    int site0 = bid * 64;                  // e0 / 9 (576 = 64*9)

    // A fragments: ctx rows = batches, same for every fragment
    short8 afr[4];
    const float* arow = ctx + lq * CIN;
#pragma unroll
    for (int kc = 0; kc < 4; ++kc) {
        float4 v0 = *(const float4*)(arow + kc * 32 + quad * 8);
        float4 v1 = *(const float4*)(arow + kc * 32 + quad * 8 + 4);
        afr[kc] = pack8(v0, v1);
    }

    int ebase = e0 + wid * 144;            // 9 fragments of 16 rows per wave
#pragma unroll 3
    for (int j = 0; j < 9; ++j) {
        unsigned e = ebase + j * 16 + lq;  // this lane's wk row (contiguous in lq)
        const float* wrow = wk + (size_t)e * CIN;
        floatx4 acc = {0.f, 0.f, 0.f, 0.f};
#pragma unroll
        for (int kc = 0; kc < 4; ++kc) {
            float4 v0 = *(const float4*)(wrow + kc * 32 + quad * 8);
            float4 v1 = *(const float4*)(wrow + kc * 32 + quad * 8 + 4);
            short8 bfr = pack8(v0, v1);
            acc = __builtin_amdgcn_mfma_f32_16x16x32_bf16(afr[kc], bfr, acc, 0, 0, 0);
        }
        unsigned site = e / 9u, tap = e - site * 9u;   // compiler emits magic-mul
        unsigned oc = site >> 7, ic = site & 127;
        unsigned ds = site - site0;                    // 0..63
        float bke = bk[e], bse = base[e];
#pragma unroll
        for (int r = 0; r < 4; ++r) {
            int b = quad * 4 + r;
            float s = 1.f / (1.f + __expf(-(acc[r] + bke)));
            float v = bse * s * aout[b * COUT + oc] * ain[b * CIN + ic] * asp[b * 16 + tap];
            s_res[tap * 1024 + b * 64 + ds] = f2b(v);
        }
    }
    __syncthreads();
    // write-out: 144 (tap,b) runs x 128 B, coalesced uint4 chunks
    for (int c = threadIdx.x; c < 1152; c += 256) {
        int q = c & 7, rb = c >> 3;
        int b = rb & 15, tap = rb >> 4;
        uint4 v = *(const uint4*)(s_res + tap * 1024 + b * 64 + q * 8);
        *(uint4*)(dyn + (size_t)b * NE + tap * 32768 + site0 + q * 8) = v;
    }
}

// ---------------------------------------------------------------------------
// K4: conv as MFMA implicit GEMM. 448 blocks, XCD-swizzled. Block: 64 oc x 8
// output rows. Staging via global_load_lds width=16.
__global__ __launch_bounds__(256, 2) void k_conv(
    const unsigned short* __restrict__ xt, const unsigned short* __restrict__ dyn,
    const float* __restrict__ bias, float* __restrict__ out,
    const unsigned short* __restrict__ zp) {
    __shared__ char s_x[640 * 64];   // 40 KiB
    __shared__ char s_a[576 * 64];   // 36 KiB
    int id  = blockIdx.x;
    int low = id & 7;
    int q   = id >> 3;
    int r   = q % 7;
    int phi = q / 7;
    int p   = phi * 8 + low;
    int oc0 = (p >> 4) * 64;
    int b   = p & 15;
    int r0  = r * 8;

    int tid = threadIdx.x;
    int wn = tid >> 6, l = tid & 63, lq = l & 15, quad = l >> 4;
    const unsigned short* xtb  = xt  + (size_t)b * HW * CIN;
    const unsigned short* dynb = dyn + (size_t)b * NE;

    int colx = wn * 16 + (l >> 2);
    int gxs  = colx - 1;
    bool gxok = (unsigned)gxs < (unsigned)WW;
    const unsigned short* zsrc = zp + l * 8;   // 16 B of zeros per lane

    int pixaddr[7];
#pragma unroll
    for (int nf = 0; nf < 7; ++nf) {
        int n = nf * 16 + lq;
        int tr = wn * 2 + n / 56, col = n % 56;
        pixaddr[nf] = (tr * 64 + col) * 64 + quad * 16;
    }

    floatx4 acc[4][7];
#pragma unroll
    for (int i = 0; i < 4; ++i)
#pragma unroll
        for (int j = 0; j < 7; ++j) acc[i][j] = (floatx4){0.f, 0.f, 0.f, 0.f};

    for (int kc = 0; kc < 4; ++kc) {
        __syncthreads();
#pragma unroll
        for (int ry = 0; ry < 10; ++ry) {
            int gy = r0 + ry - 1;
            const unsigned short* src =
                (gxok && (unsigned)gy < (unsigned)HH)
                    ? xtb + (size_t)(gy * WW + gxs) * CIN + kc * 32 + (l & 3) * 8
                    : zsrc;
            gl_lds16(src, s_x + ry * 4096 + wn * 1024);
        }
#pragma unroll
        for (int i = 0; i < 9; ++i) {
            int u = i * 256 + tid;
            int icq2 = u & 3, oc = (u >> 2) & 63, tap = u >> 8;
            gl_lds16(dynb + (size_t)(tap * COUT + oc0 + oc) * CIN + kc * 32 + icq2 * 8,
                     s_a + i * 4096 + wn * 1024);
        }
        __syncthreads();
        __builtin_amdgcn_s_setprio(1);
#pragma unroll
        for (int tap = 0; tap < 9; ++tap) {
            short8 af[4];
#pragma unroll
            for (int mf = 0; mf < 4; ++mf)
                af[mf] = *(const short8*)(s_a + (tap * 64 + mf * 16 + lq) * 64 + quad * 16);
            int toff = (tap / 3) * 4096 + (tap % 3) * 64;
#pragma unroll
            for (int nf = 0; nf < 7; ++nf) {
                short8 bf = *(const short8*)(s_x + pixaddr[nf] + toff);
#pragma unroll
                for (int mf = 0; mf < 4; ++mf)
                    acc[mf][nf] = __builtin_amdgcn_mfma_f32_16x16x32_bf16(af[mf], bf, acc[mf][nf], 0, 0, 0);
            }
        }
        __builtin_amdgcn_s_setprio(0);
    }

#pragma unroll
    for (int mf = 0; mf < 4; ++mf) {
#pragma unroll
        for (int rr = 0; rr < 4; ++rr) {
            int oc = oc0 + mf * 16 + quad * 4 + rr;
            float bs = bias[oc];
            float* ob = out + (size_t)(b * COUT + oc) * HW + (r0 + wn * 2) * 56 + lq;
#pragma unroll
            for (int nf = 0; nf < 7; ++nf)
                ob[nf * 16] = acc[mf][nf][rr] + bs;
        }
    }
}

// ---------------------------------------------------------------------------
extern "C" void kernel_launch(void* const* d_in, const int* in_sizes, int n_in,
                              void* d_out, int out_size, void* d_ws, size_t ws_size,
                              hipStream_t stream) {
    const float* x    = (const float*)d_in[0];
    const float* base = (const float*)d_in[1];
    const float* bias = (const float*)d_in[2];
    const float* wsp  = (const float*)d_in[3];
    const float* bsp  = (const float*)d_in[4];
    const float* win  = (const float*)d_in[5];
    const float* bin  = (const float*)d_in[6];
    const float* wout = (const float*)d_in[7];
    const float* bout = (const float*)d_in[8];
    const float* wk   = (const float*)d_in[9];
    const float* bk   = (const float*)d_in[10];
    float* out = (float*)d_out;
    char* ws = (char*)d_ws;

    float* ctx  = (float*)(ws + WSB_CTX);
    float* asp  = (float*)(ws + WSB_ASP);
    float* ain  = (float*)(ws + WSB_AIN);
    float* aout = (float*)(ws + WSB_AOUT);
    float* zp   = (float*)(ws + WSB_ZP);
    unsigned short* xt  = (unsigned short*)(ws + WSB_XT);
    unsigned short* dyn = (unsigned short*)(ws + WSB_DYN);

    k_context<<<BATCH * CIN, 256, 0, stream>>>(x, ctx, zp);
    k_attn<<<(BATCH * 393) / 4, 256, 0, stream>>>(ctx, wsp, bsp, win, bin, wout, bout, asp, ain, aout);
    k_fat<<<XT_BLOCKS + BUILD_BLOCKS, 256, 0, stream>>>(x, xt, ctx, wk, bk, base, asp, ain, aout, dyn);
    k_conv<<<448, 256, 0, stream>>>(xt, dyn, bias, out, (const unsigned short*)zp);
}

// Round 4
// 313.903 us; speedup vs baseline: 1.0643x; 1.0643x over previous
//
#include <hip/hip_runtime.h>
#include <hip/hip_bf16.h>
#include <math.h>

#define BATCH 16
#define CIN   128
#define COUT  256
#define HH    56
#define WW    56
#define HW    3136
#define NTAP  9
#define NE    (COUT*CIN*NTAP)   // 294912

typedef short short8 __attribute__((ext_vector_type(8)));
typedef float floatx4 __attribute__((ext_vector_type(4)));

// workspace layout (byte offsets, all 256-aligned)
#define WSB_CTX   0                          // fp32 [16][128]
#define WSB_ASP   8192                       // fp32 [16][16] (9 used)
#define WSB_AIN   9472                       // fp32 [16][128]
#define WSB_AOUT  17664                      // fp32 [16][256]
#define WSB_ZP    34048                      // 4096 B of zeros (conv halo source)
#define WSB_XT    38144                      // bf16 [16][3136][128]
#define WSB_DYN   (WSB_XT + BATCH*HW*CIN*2)  // bf16 [16][9][256][128]  (tap,oc,ic)

// fp32 -> bf16 RNE
static __device__ inline unsigned short f2b(float f) {
    union { float f; unsigned u; } v; v.f = f;
    unsigned r = v.u + 0x7FFF + ((v.u >> 16) & 1);
    return (unsigned short)(r >> 16);
}
static __device__ inline short8 pack8(float4 a, float4 b) {
    short8 r;
    r[0] = (short)f2b(a.x); r[1] = (short)f2b(a.y); r[2] = (short)f2b(a.z); r[3] = (short)f2b(a.w);
    r[4] = (short)f2b(b.x); r[5] = (short)f2b(b.y); r[6] = (short)f2b(b.z); r[7] = (short)f2b(b.w);
    return r;
}

// async global->LDS, 16B per lane; LDS dst = wave-uniform base + lane*16
typedef const __attribute__((address_space(1))) void* gas_ptr;
typedef __attribute__((address_space(3))) void* las_ptr;
static __device__ __forceinline__ void gl_lds16(const void* g, void* l) {
    __builtin_amdgcn_global_load_lds((gas_ptr)g, (las_ptr)l, 16, 0, 0);
}

// ---------------------------------------------------------------------------
// K1: context[b,c] = mean(x[b,c,:,:]); block 0 also zeroes the conv zero-page
__global__ void k_context(const float* __restrict__ x, float* __restrict__ ctx,
                          float* __restrict__ zp) {
    int bc = blockIdx.x;
    if (bc == 0 && threadIdx.x < 64) {
        uint4 z = {0u, 0u, 0u, 0u};
        ((uint4*)zp)[threadIdx.x] = z;   // 1024 B of zeros
    }
    const float4* p = (const float4*)(x + (size_t)bc * HW);
    float s = 0.f;
    for (int i = threadIdx.x; i < HW / 4; i += 256) { float4 v = p[i]; s += v.x + v.y + v.z + v.w; }
    for (int off = 32; off; off >>= 1) s += __shfl_down(s, off, 64);
    __shared__ float red[4];
    if ((threadIdx.x & 63) == 0) red[threadIdx.x >> 6] = s;
    __syncthreads();
    if (threadIdx.x == 0) ctx[bc] = (red[0] + red[1] + red[2] + red[3]) * (1.f / (float)HW);
}

// ---------------------------------------------------------------------------
// K2: small gates — one wave per GEMV row
__global__ void k_attn(const float* __restrict__ ctx,
                       const float* __restrict__ wsp, const float* __restrict__ bsp,
                       const float* __restrict__ win, const float* __restrict__ bin,
                       const float* __restrict__ wout, const float* __restrict__ bout,
                       float* __restrict__ asp, float* __restrict__ ain, float* __restrict__ aout) {
    int R = blockIdx.x * 4 + (threadIdx.x >> 6);
    int lane = threadIdx.x & 63;
    int b = R / 393, r = R % 393;
    const float* w; float bias; float* o;
    if (r < 9)        { w = wsp  + r * CIN;         bias = bsp[r];         o = asp  + b * 16  + r; }
    else if (r < 137) { w = win  + (r - 9) * CIN;   bias = bin[r - 9];     o = ain  + b * CIN + (r - 9); }
    else              { w = wout + (r - 137) * CIN; bias = bout[r - 137];  o = aout + b * COUT + (r - 137); }
    float2 wv = ((const float2*)w)[lane];
    float2 cv = ((const float2*)(ctx + b * CIN))[lane];
    float d = wv.x * cv.x + wv.y * cv.y;
    for (int off = 32; off; off >>= 1) d += __shfl_down(d, off, 64);
    if (lane == 0) *o = 1.f / (1.f + __expf(-(d + bias)));
}

// ---------------------------------------------------------------------------
// K3 fat kernel: blocks [0,784) do the x transpose+cast (xt), blocks
// [784, 784+1152) do the dyn build.
// BUILD v3 (latency fix — v2 was 106us @ 21% occupancy, everything idle):
//   * 1152 blocks (4.5 blocks/CU -> ~18 waves/CU) instead of 512
//   * 256 contiguous wk rows per block; 4 fragments/wave FULLY unrolled
//     (4-deep load pipeline per wave)
//   * contiguous reads kept; LDS-staged write-out generalized to
//     non-site-aligned blocks: per (tap,b) the owned sites form a
//     contiguous run [sLo,sHi] -> coalesced ~58B runs by half-waves
//   * s_res tap stride padded (530) so tap-adjacent lanes hit distinct banks
#define XT_BLOCKS    784          // 49 * 16
#define BUILD_BLOCKS 1152         // NE / 256
__global__ void k_fat(const float* __restrict__ x, unsigned short* __restrict__ xt,
                      const float* __restrict__ ctx, const float* __restrict__ wk,
                      const float* __restrict__ bk, const float* __restrict__ base,
                      const float* __restrict__ asp, const float* __restrict__ ain,
                      const float* __restrict__ aout, unsigned short* __restrict__ dyn) {
    __shared__ unsigned short s_res[9 * 530 + 16];   // [tap(pad 530)][b*32+ds], ~9.6 KB
    if (blockIdx.x < XT_BLOCKS) {
        // ---- xt: [b][pix][ic] bf16; thread: 1 pixel x 32 ic ----
        int bid = blockIdx.x;
        int b = bid / 49;
        int p = (bid % 49) * 64 + (threadIdx.x & 63);
        int icq = threadIdx.x >> 6;
        const float* xb = x + (size_t)b * CIN * HW + p;
        unsigned short tmp[32];
#pragma unroll
        for (int j = 0; j < 32; ++j) tmp[j] = f2b(xb[(size_t)(icq * 32 + j) * HW]);
        uint4* dst = (uint4*)(xt + ((size_t)b * HW + p) * CIN + icq * 32);
        const uint4* s = (const uint4*)tmp;
        dst[0] = s[0]; dst[1] = s[1]; dst[2] = s[2]; dst[3] = s[3];
        return;
    }
    // ---- build v3 ----
    int bid = blockIdx.x - XT_BLOCKS;      // 0..1151
    int wid = threadIdx.x >> 6, l = threadIdx.x & 63;
    int lq = l & 15, quad = l >> 4;
    int e0      = bid * 256;               // first wk row of this block
    int siteMin = e0 / 9;

    // A fragments: ctx rows = batches, same for every fragment
    short8 afr[4];
    const float* arow = ctx + lq * CIN;
#pragma unroll
    for (int kc = 0; kc < 4; ++kc) {
        float4 v0 = *(const float4*)(arow + kc * 32 + quad * 8);
        float4 v1 = *(const float4*)(arow + kc * 32 + quad * 8 + 4);
        afr[kc] = pack8(v0, v1);
    }

    int ebase = e0 + wid * 64;             // 4 fragments of 16 rows per wave
    // phase 1: load + pack all 4 fragments (32 x 16B loads in flight)
    short8 bfr[4][4];
    float bke[4], bse[4];
#pragma unroll
    for (int j = 0; j < 4; ++j) {
        unsigned e = ebase + j * 16 + lq;  // lane's wk row (contiguous in lq)
        const float* wrow = wk + (size_t)e * CIN;
#pragma unroll
        for (int kc = 0; kc < 4; ++kc) {
            float4 v0 = *(const float4*)(wrow + kc * 32 + quad * 8);
            float4 v1 = *(const float4*)(wrow + kc * 32 + quad * 8 + 4);
            bfr[j][kc] = pack8(v0, v1);
        }
        bke[j] = bk[e]; bse[j] = base[e];
    }
    // phase 2: 16 MFMAs
    floatx4 acc[4];
#pragma unroll
    for (int j = 0; j < 4; ++j) acc[j] = (floatx4){0.f, 0.f, 0.f, 0.f};
#pragma unroll
    for (int j = 0; j < 4; ++j)
#pragma unroll
        for (int kc = 0; kc < 4; ++kc)
            acc[j] = __builtin_amdgcn_mfma_f32_16x16x32_bf16(afr[kc], bfr[j][kc], acc[j], 0, 0, 0);
    // phase 3: gate + stage into LDS
#pragma unroll
    for (int j = 0; j < 4; ++j) {
        unsigned e = ebase + j * 16 + lq;
        unsigned site = e / 9u, tap = e - site * 9u;
        unsigned oc = site >> 7, ic = site & 127;
        unsigned ds = site - siteMin;                  // 0..29
#pragma unroll
        for (int r = 0; r < 4; ++r) {
            int b = quad * 4 + r;
            float s = 1.f / (1.f + __expf(-(acc[j][r] + bke[j])));
            float v = bse[j] * s * aout[b * COUT + oc] * ain[b * CIN + ic] * asp[b * 16 + tap];
            s_res[tap * 530 + b * 32 + ds] = f2b(v);
        }
    }
    __syncthreads();
    // write-out: 144 (tap,b) runs, one per half-wave, ~58B contiguous each
    int hw_id = threadIdx.x >> 5;          // 0..7
    int hl    = threadIdx.x & 31;
#pragma unroll
    for (int it = 0; it < 18; ++it) {
        int pair = it * 8 + hw_id;         // 0..143
        int t = pair >> 4, b = pair & 15;
        int sLo = (e0 - t + 8) / 9;        // e0-t+8 >= 0
        int sHi = (e0 + 255 - t) / 9;
        int cnt = sHi - sLo + 1;           // <= 30
        if (hl < cnt) {
            unsigned short v = s_res[t * 530 + b * 32 + (sLo - siteMin) + hl];
            dyn[(size_t)b * NE + t * 32768 + sLo + hl] = v;
        }
    }
}

// ---------------------------------------------------------------------------
// K4: conv as MFMA implicit GEMM. 448 blocks, XCD-swizzled. Block: 64 oc x 8
// output rows. Staging via global_load_lds width=16.
__global__ __launch_bounds__(256, 2) void k_conv(
    const unsigned short* __restrict__ xt, const unsigned short* __restrict__ dyn,
    const float* __restrict__ bias, float* __restrict__ out,
    const unsigned short* __restrict__ zp) {
    __shared__ char s_x[640 * 64];   // 40 KiB
    __shared__ char s_a[576 * 64];   // 36 KiB
    int id  = blockIdx.x;
    int low = id & 7;
    int q   = id >> 3;
    int r   = q % 7;
    int phi = q / 7;
    int p   = phi * 8 + low;
    int oc0 = (p >> 4) * 64;
    int b   = p & 15;
    int r0  = r * 8;

    int tid = threadIdx.x;
    int wn = tid >> 6, l = tid & 63, lq = l & 15, quad = l >> 4;
    const unsigned short* xtb  = xt  + (size_t)b * HW * CIN;
    const unsigned short* dynb = dyn + (size_t)b * NE;

    int colx = wn * 16 + (l >> 2);
    int gxs  = colx - 1;
    bool gxok = (unsigned)gxs < (unsigned)WW;
    const unsigned short* zsrc = zp + l * 8;   // 16 B of zeros per lane

    int pixaddr[7];
#pragma unroll
    for (int nf = 0; nf < 7; ++nf) {
        int n = nf * 16 + lq;
        int tr = wn * 2 + n / 56, col = n % 56;
        pixaddr[nf] = (tr * 64 + col) * 64 + quad * 16;
    }

    floatx4 acc[4][7];
#pragma unroll
    for (int i = 0; i < 4; ++i)
#pragma unroll
        for (int j = 0; j < 7; ++j) acc[i][j] = (floatx4){0.f, 0.f, 0.f, 0.f};

    for (int kc = 0; kc < 4; ++kc) {
        __syncthreads();
#pragma unroll
        for (int ry = 0; ry < 10; ++ry) {
            int gy = r0 + ry - 1;
            const unsigned short* src =
                (gxok && (unsigned)gy < (unsigned)HH)
                    ? xtb + (size_t)(gy * WW + gxs) * CIN + kc * 32 + (l & 3) * 8
                    : zsrc;
            gl_lds16(src, s_x + ry * 4096 + wn * 1024);
        }
#pragma unroll
        for (int i = 0; i < 9; ++i) {
            int u = i * 256 + tid;
            int icq2 = u & 3, oc = (u >> 2) & 63, tap = u >> 8;
            gl_lds16(dynb + (size_t)(tap * COUT + oc0 + oc) * CIN + kc * 32 + icq2 * 8,
                     s_a + i * 4096 + wn * 1024);
        }
        __syncthreads();
        __builtin_amdgcn_s_setprio(1);
#pragma unroll
        for (int tap = 0; tap < 9; ++tap) {
            short8 af[4];
#pragma unroll
            for (int mf = 0; mf < 4; ++mf)
                af[mf] = *(const short8*)(s_a + (tap * 64 + mf * 16 + lq) * 64 + quad * 16);
            int toff = (tap / 3) * 4096 + (tap % 3) * 64;
#pragma unroll
            for (int nf = 0; nf < 7; ++nf) {
                short8 bf = *(const short8*)(s_x + pixaddr[nf] + toff);
#pragma unroll
                for (int mf = 0; mf < 4; ++mf)
                    acc[mf][nf] = __builtin_amdgcn_mfma_f32_16x16x32_bf16(af[mf], bf, acc[mf][nf], 0, 0, 0);
            }
        }
        __builtin_amdgcn_s_setprio(0);
    }

#pragma unroll
    for (int mf = 0; mf < 4; ++mf) {
#pragma unroll
        for (int rr = 0; rr < 4; ++rr) {
            int oc = oc0 + mf * 16 + quad * 4 + rr;
            float bs = bias[oc];
            float* ob = out + (size_t)(b * COUT + oc) * HW + (r0 + wn * 2) * 56 + lq;
#pragma unroll
            for (int nf = 0; nf < 7; ++nf)
                ob[nf * 16] = acc[mf][nf][rr] + bs;
        }
    }
}

// ---------------------------------------------------------------------------
extern "C" void kernel_launch(void* const* d_in, const int* in_sizes, int n_in,
                              void* d_out, int out_size, void* d_ws, size_t ws_size,
                              hipStream_t stream) {
    const float* x    = (const float*)d_in[0];
    const float* base = (const float*)d_in[1];
    const float* bias = (const float*)d_in[2];
    const float* wsp  = (const float*)d_in[3];
    const float* bsp  = (const float*)d_in[4];
    const float* win  = (const float*)d_in[5];
    const float* bin  = (const float*)d_in[6];
    const float* wout = (const float*)d_in[7];
    const float* bout = (const float*)d_in[8];
    const float* wk   = (const float*)d_in[9];
    const float* bk   = (const float*)d_in[10];
    float* out = (float*)d_out;
    char* ws = (char*)d_ws;

    float* ctx  = (float*)(ws + WSB_CTX);
    float* asp  = (float*)(ws + WSB_ASP);
    float* ain  = (float*)(ws + WSB_AIN);
    float* aout = (float*)(ws + WSB_AOUT);
    float* zp   = (float*)(ws + WSB_ZP);
    unsigned short* xt  = (unsigned short*)(ws + WSB_XT);
    unsigned short* dyn = (unsigned short*)(ws + WSB_DYN);

    k_context<<<BATCH * CIN, 256, 0, stream>>>(x, ctx, zp);
    k_attn<<<(BATCH * 393) / 4, 256, 0, stream>>>(ctx, wsp, bsp, win, bin, wout, bout, asp, ain, aout);
    k_fat<<<XT_BLOCKS + BUILD_BLOCKS, 256, 0, stream>>>(x, xt, ctx, wk, bk, base, asp, ain, aout, dyn);
    k_conv<<<448, 256, 0, stream>>>(xt, dyn, bias, out, (const unsigned short*)zp);
}

// Round 5
// 313.536 us; speedup vs baseline: 1.0656x; 1.0012x over previous
//
#include <hip/hip_runtime.h>
#include <hip/hip_bf16.h>
#include <math.h>

#define BATCH 16
#define CIN   128
#define COUT  256
#define HH    56
#define WW    56
#define HW    3136
#define NTAP  9
#define NE    (COUT*CIN*NTAP)   // 294912

typedef short short8 __attribute__((ext_vector_type(8)));
typedef float floatx4 __attribute__((ext_vector_type(4)));

// workspace layout (byte offsets, all 256-aligned)
#define WSB_CTX   0                          // fp32 [16][128]
#define WSB_ASP   8192                       // fp32 [16][16] (9 used)
#define WSB_AIN   9472                       // fp32 [16][128]
#define WSB_AOUT  17664                      // fp32 [16][256]
#define WSB_ZP    34048                      // 4096 B of zeros (conv halo source)
#define WSB_XT    38144                      // bf16 [16][3136][128]
#define WSB_DYN   (WSB_XT + BATCH*HW*CIN*2)  // bf16 [16][9][256][128]  (tap,oc,ic)

// fp32 -> bf16 RNE
static __device__ inline unsigned short f2b(float f) {
    union { float f; unsigned u; } v; v.f = f;
    unsigned r = v.u + 0x7FFF + ((v.u >> 16) & 1);
    return (unsigned short)(r >> 16);
}
static __device__ inline short8 pack8(float4 a, float4 b) {
    short8 r;
    r[0] = (short)f2b(a.x); r[1] = (short)f2b(a.y); r[2] = (short)f2b(a.z); r[3] = (short)f2b(a.w);
    r[4] = (short)f2b(b.x); r[5] = (short)f2b(b.y); r[6] = (short)f2b(b.z); r[7] = (short)f2b(b.w);
    return r;
}

// async global->LDS, 16B per lane; LDS dst = wave-uniform base + lane*16
typedef const __attribute__((address_space(1))) void* gas_ptr;
typedef __attribute__((address_space(3))) void* las_ptr;
static __device__ __forceinline__ void gl_lds16(const void* g, void* l) {
    __builtin_amdgcn_global_load_lds((gas_ptr)g, (las_ptr)l, 16, 0, 0);
}

// ---------------------------------------------------------------------------
// K1: context[b,c] = mean(x[b,c,:,:]); block 0 also zeroes the conv zero-page
__global__ void k_context(const float* __restrict__ x, float* __restrict__ ctx,
                          float* __restrict__ zp) {
    int bc = blockIdx.x;
    if (bc == 0 && threadIdx.x < 64) {
        uint4 z = {0u, 0u, 0u, 0u};
        ((uint4*)zp)[threadIdx.x] = z;   // 1024 B of zeros
    }
    const float4* p = (const float4*)(x + (size_t)bc * HW);
    float s = 0.f;
    for (int i = threadIdx.x; i < HW / 4; i += 256) { float4 v = p[i]; s += v.x + v.y + v.z + v.w; }
    for (int off = 32; off; off >>= 1) s += __shfl_down(s, off, 64);
    __shared__ float red[4];
    if ((threadIdx.x & 63) == 0) red[threadIdx.x >> 6] = s;
    __syncthreads();
    if (threadIdx.x == 0) ctx[bc] = (red[0] + red[1] + red[2] + red[3]) * (1.f / (float)HW);
}

// ---------------------------------------------------------------------------
// K2: small gates — one wave per GEMV row
__global__ void k_attn(const float* __restrict__ ctx,
                       const float* __restrict__ wsp, const float* __restrict__ bsp,
                       const float* __restrict__ win, const float* __restrict__ bin,
                       const float* __restrict__ wout, const float* __restrict__ bout,
                       float* __restrict__ asp, float* __restrict__ ain, float* __restrict__ aout) {
    int R = blockIdx.x * 4 + (threadIdx.x >> 6);
    int lane = threadIdx.x & 63;
    int b = R / 393, r = R % 393;
    const float* w; float bias; float* o;
    if (r < 9)        { w = wsp  + r * CIN;         bias = bsp[r];         o = asp  + b * 16  + r; }
    else if (r < 137) { w = win  + (r - 9) * CIN;   bias = bin[r - 9];     o = ain  + b * CIN + (r - 9); }
    else              { w = wout + (r - 137) * CIN; bias = bout[r - 137];  o = aout + b * COUT + (r - 137); }
    float2 wv = ((const float2*)w)[lane];
    float2 cv = ((const float2*)(ctx + b * CIN))[lane];
    float d = wv.x * cv.x + wv.y * cv.y;
    for (int off = 32; off; off >>= 1) d += __shfl_down(d, off, 64);
    if (lane == 0) *o = 1.f / (1.f + __expf(-(d + bias)));
}

// ---------------------------------------------------------------------------
// K3a: xt transpose/cast, v2 (LDS transpose).
// Block = 32 channels x 256 pixels of one batch. Reads: 1KB-contiguous
// per wave-instr (4x better page locality than the old 256B channel-hop);
// stores: each lane writes a full 64B xt row-slice (64B sectors, vs old
// 16B fragments). Separate kernel -> small VGPR/LDS, high occupancy,
// no longer capped by the build path's register budget.
#define XT_V2_BLOCKS (BATCH * 4 * 13)   // 16 b x 4 ch-groups x 13 px-chunks
__global__ __launch_bounds__(256) void k_xt(const float* __restrict__ x,
                                            unsigned short* __restrict__ xt) {
    __shared__ unsigned short s[32 * 264];   // [c][px pad 264] 16.9 KB
    int bid = blockIdx.x;
    int b = bid / 52, rem = bid % 52;
    int chg = rem / 13, ck = rem % 13;
    int px0 = ck * 256;
    int npx = HW - px0; if (npx > 256) npx = 256;   // 256, tail chunk 64
    int tid = threadIdx.x;
    const float* xb = x + ((size_t)(b * CIN + chg * 32)) * HW + px0;
#pragma unroll
    for (int pass = 0; pass < 8; ++pass) {
        int i = pass * 256 + tid;
        int c = i >> 6, p4 = i & 63;        // wave: one channel, 64 float4 = 1KB
        int px = p4 * 4;
        if (px < npx) {
            float4 v = *(const float4*)(xb + (size_t)c * HW + px);
            unsigned short h[4] = {f2b(v.x), f2b(v.y), f2b(v.z), f2b(v.w)};
            *(uint2*)(&s[c * 264 + px]) = *(const uint2*)h;
        }
    }
    __syncthreads();
    int px = tid;
    if (px < npx) {
        unsigned short h[32];
#pragma unroll
        for (int c = 0; c < 32; ++c) h[c] = s[c * 264 + px];  // 2-way free
        uint4* dst = (uint4*)(xt + ((size_t)b * HW + px0 + px) * CIN + chg * 32);
        const uint4* q = (const uint4*)h;
        dst[0] = q[0]; dst[1] = q[1]; dst[2] = q[2]; dst[3] = q[3];
    }
}

// ---------------------------------------------------------------------------
// K3b: dyn build v4 = v3's verified logic, own kernel, launch_bounds(256,4)
// (<=128 VGPR -> 4 waves/SIMD), fragment work in 2+2 pairs to keep register
// pressure down. Contiguous wk streams + LDS-staged coalesced write-out kept.
#define BUILD_BLOCKS 1152         // NE / 256
__global__ __launch_bounds__(256, 4) void k_build(
    const float* __restrict__ ctx, const float* __restrict__ wk,
    const float* __restrict__ bk, const float* __restrict__ base,
    const float* __restrict__ asp, const float* __restrict__ ain,
    const float* __restrict__ aout, unsigned short* __restrict__ dyn) {
    __shared__ unsigned short s_res[9 * 530 + 16];   // [tap(pad 530)][b*32+ds]
    int bid = blockIdx.x;
    int wid = threadIdx.x >> 6, l = threadIdx.x & 63;
    int lq = l & 15, quad = l >> 4;
    int e0      = bid * 256;               // first wk row of this block
    int siteMin = e0 / 9;

    // A fragments: ctx rows = batches
    short8 afr[4];
    const float* arow = ctx + lq * CIN;
#pragma unroll
    for (int kc = 0; kc < 4; ++kc) {
        float4 v0 = *(const float4*)(arow + kc * 32 + quad * 8);
        float4 v1 = *(const float4*)(arow + kc * 32 + quad * 8 + 4);
        afr[kc] = pack8(v0, v1);
    }

    int ebase = e0 + wid * 64;             // 4 fragments of 16 rows per wave
#pragma unroll
    for (int jp = 0; jp < 2; ++jp) {
        short8 bfr[2][4];
        float bke[2], bse[2];
        floatx4 acc[2];
#pragma unroll
        for (int u = 0; u < 2; ++u) {
            int j = jp * 2 + u;
            unsigned e = ebase + j * 16 + lq;       // lane's wk row (contig in lq)
            const float* wrow = wk + (size_t)e * CIN;
#pragma unroll
            for (int kc = 0; kc < 4; ++kc) {
                float4 v0 = *(const float4*)(wrow + kc * 32 + quad * 8);
                float4 v1 = *(const float4*)(wrow + kc * 32 + quad * 8 + 4);
                bfr[u][kc] = pack8(v0, v1);
            }
            bke[u] = bk[e]; bse[u] = base[e];
            acc[u] = (floatx4){0.f, 0.f, 0.f, 0.f};
        }
#pragma unroll
        for (int u = 0; u < 2; ++u)
#pragma unroll
            for (int kc = 0; kc < 4; ++kc)
                acc[u] = __builtin_amdgcn_mfma_f32_16x16x32_bf16(afr[kc], bfr[u][kc], acc[u], 0, 0, 0);
#pragma unroll
        for (int u = 0; u < 2; ++u) {
            int j = jp * 2 + u;
            unsigned e = ebase + j * 16 + lq;
            unsigned site = e / 9u, tap = e - site * 9u;
            unsigned oc = site >> 7, ic = site & 127;
            unsigned ds = site - siteMin;            // 0..29
#pragma unroll
            for (int r = 0; r < 4; ++r) {
                int bb = quad * 4 + r;
                float sg = 1.f / (1.f + __expf(-(acc[u][r] + bke[u])));
                float v = bse[u] * sg * aout[bb * COUT + oc] * ain[bb * CIN + ic] * asp[bb * 16 + tap];
                s_res[tap * 530 + bb * 32 + ds] = f2b(v);
            }
        }
    }
    __syncthreads();
    // write-out: 144 (tap,b) runs, one per half-wave, ~58B contiguous each
    int hw_id = threadIdx.x >> 5;          // 0..7
    int hl    = threadIdx.x & 31;
#pragma unroll
    for (int it = 0; it < 18; ++it) {
        int pair = it * 8 + hw_id;         // 0..143
        int t = pair >> 4, b = pair & 15;
        int sLo = (e0 - t + 8) / 9;        // e0-t+8 >= 0
        int sHi = (e0 + 255 - t) / 9;
        int cnt = sHi - sLo + 1;           // <= 30
        if (hl < cnt) {
            unsigned short v = s_res[t * 530 + b * 32 + (sLo - siteMin) + hl];
            dyn[(size_t)b * NE + t * 32768 + sLo + hl] = v;
        }
    }
}

// ---------------------------------------------------------------------------
// K4: conv as MFMA implicit GEMM. 448 blocks, XCD-swizzled. Block: 64 oc x 8
// output rows. Staging via global_load_lds width=16.
__global__ __launch_bounds__(256, 2) void k_conv(
    const unsigned short* __restrict__ xt, const unsigned short* __restrict__ dyn,
    const float* __restrict__ bias, float* __restrict__ out,
    const unsigned short* __restrict__ zp) {
    __shared__ char s_x[640 * 64];   // 40 KiB
    __shared__ char s_a[576 * 64];   // 36 KiB
    int id  = blockIdx.x;
    int low = id & 7;
    int q   = id >> 3;
    int r   = q % 7;
    int phi = q / 7;
    int p   = phi * 8 + low;
    int oc0 = (p >> 4) * 64;
    int b   = p & 15;
    int r0  = r * 8;

    int tid = threadIdx.x;
    int wn = tid >> 6, l = tid & 63, lq = l & 15, quad = l >> 4;
    const unsigned short* xtb  = xt  + (size_t)b * HW * CIN;
    const unsigned short* dynb = dyn + (size_t)b * NE;

    int colx = wn * 16 + (l >> 2);
    int gxs  = colx - 1;
    bool gxok = (unsigned)gxs < (unsigned)WW;
    const unsigned short* zsrc = zp + l * 8;   // 16 B of zeros per lane

    int pixaddr[7];
#pragma unroll
    for (int nf = 0; nf < 7; ++nf) {
        int n = nf * 16 + lq;
        int tr = wn * 2 + n / 56, col = n % 56;
        pixaddr[nf] = (tr * 64 + col) * 64 + quad * 16;
    }

    floatx4 acc[4][7];
#pragma unroll
    for (int i = 0; i < 4; ++i)
#pragma unroll
        for (int j = 0; j < 7; ++j) acc[i][j] = (floatx4){0.f, 0.f, 0.f, 0.f};

    for (int kc = 0; kc < 4; ++kc) {
        __syncthreads();
#pragma unroll
        for (int ry = 0; ry < 10; ++ry) {
            int gy = r0 + ry - 1;
            const unsigned short* src =
                (gxok && (unsigned)gy < (unsigned)HH)
                    ? xtb + (size_t)(gy * WW + gxs) * CIN + kc * 32 + (l & 3) * 8
                    : zsrc;
            gl_lds16(src, s_x + ry * 4096 + wn * 1024);
        }
#pragma unroll
        for (int i = 0; i < 9; ++i) {
            int u = i * 256 + tid;
            int icq2 = u & 3, oc = (u >> 2) & 63, tap = u >> 8;
            gl_lds16(dynb + (size_t)(tap * COUT + oc0 + oc) * CIN + kc * 32 + icq2 * 8,
                     s_a + i * 4096 + wn * 1024);
        }
        __syncthreads();
        __builtin_amdgcn_s_setprio(1);
#pragma unroll
        for (int tap = 0; tap < 9; ++tap) {
            short8 af[4];
#pragma unroll
            for (int mf = 0; mf < 4; ++mf)
                af[mf] = *(const short8*)(s_a + (tap * 64 + mf * 16 + lq) * 64 + quad * 16);
            int toff = (tap / 3) * 4096 + (tap % 3) * 64;
#pragma unroll
            for (int nf = 0; nf < 7; ++nf) {
                short8 bf = *(const short8*)(s_x + pixaddr[nf] + toff);
#pragma unroll
                for (int mf = 0; mf < 4; ++mf)
                    acc[mf][nf] = __builtin_amdgcn_mfma_f32_16x16x32_bf16(af[mf], bf, acc[mf][nf], 0, 0, 0);
            }
        }
        __builtin_amdgcn_s_setprio(0);
    }

#pragma unroll
    for (int mf = 0; mf < 4; ++mf) {
#pragma unroll
        for (int rr = 0; rr < 4; ++rr) {
            int oc = oc0 + mf * 16 + quad * 4 + rr;
            float bs = bias[oc];
            float* ob = out + (size_t)(b * COUT + oc) * HW + (r0 + wn * 2) * 56 + lq;
#pragma unroll
            for (int nf = 0; nf < 7; ++nf)
                ob[nf * 16] = acc[mf][nf][rr] + bs;
        }
    }
}

// ---------------------------------------------------------------------------
extern "C" void kernel_launch(void* const* d_in, const int* in_sizes, int n_in,
                              void* d_out, int out_size, void* d_ws, size_t ws_size,
                              hipStream_t stream) {
    const float* x    = (const float*)d_in[0];
    const float* base = (const float*)d_in[1];
    const float* bias = (const float*)d_in[2];
    const float* wsp  = (const float*)d_in[3];
    const float* bsp  = (const float*)d_in[4];
    const float* win  = (const float*)d_in[5];
    const float* bin  = (const float*)d_in[6];
    const float* wout = (const float*)d_in[7];
    const float* bout = (const float*)d_in[8];
    const float* wk   = (const float*)d_in[9];
    const float* bk   = (const float*)d_in[10];
    float* out = (float*)d_out;
    char* ws = (char*)d_ws;

    float* ctx  = (float*)(ws + WSB_CTX);
    float* asp  = (float*)(ws + WSB_ASP);
    float* ain  = (float*)(ws + WSB_AIN);
    float* aout = (float*)(ws + WSB_AOUT);
    float* zp   = (float*)(ws + WSB_ZP);
    unsigned short* xt  = (unsigned short*)(ws + WSB_XT);
    unsigned short* dyn = (unsigned short*)(ws + WSB_DYN);

    k_context<<<BATCH * CIN, 256, 0, stream>>>(x, ctx, zp);
    k_attn<<<(BATCH * 393) / 4, 256, 0, stream>>>(ctx, wsp, bsp, win, bin, wout, bout, asp, ain, aout);
    k_xt<<<XT_V2_BLOCKS, 256, 0, stream>>>(x, xt);
    k_build<<<BUILD_BLOCKS, 256, 0, stream>>>(ctx, wk, bk, base, asp, ain, aout, dyn);
    k_conv<<<448, 256, 0, stream>>>(xt, dyn, bias, out, (const unsigned short*)zp);
}